// Round 4
// baseline (362.489 us; speedup 1.0000x reference)
//
#include <hip/hip_runtime.h>
#include <math.h>

#define B_ 32
#define H_ 64
#define W_ 48
#define C_ 256
#define G_ 8
#define D_ 32
#define BG_ (B_*G_)          // 256
#define LN_EPS_ 1e-3f
#define NPIX_ (H_*W_)        // 3072
#define XROWB 3072           // bytes per (bg,h) row of xbf: 48 px * 32 ch * 2B

typedef short bf16x8 __attribute__((ext_vector_type(8)));
typedef float f32x4 __attribute__((ext_vector_type(4)));

__device__ __forceinline__ float sigmoidf_(float v) { return 1.0f / (1.0f + expf(-v)); }

// fp32 -> bf16 round-to-nearest-even
__device__ __forceinline__ unsigned short f2bf(float f) {
    unsigned u = __float_as_uint(f);
    u = u + 0x7fffu + ((u >> 16) & 1u);
    return (unsigned short)(u >> 16);
}
__device__ __forceinline__ float bflo(unsigned u) { return __uint_as_float(u << 16); }
__device__ __forceinline__ float bfhi(unsigned u) { return __uint_as_float(u & 0xffff0000u); }

// in-row swizzled byte offset for (px, 16B-slot): linear (px<<6)+(slot<<4), XOR'd
__device__ __forceinline__ int swz16(int px, int slot) {
    return ((px << 6) + (slot << 4)) ^ ((px & 7) << 4);
}

// ---------------------------------------------------------------------------
// K0: transpose+convert conv3x3 weights to bf16, layout wbf[tap][e][d]
// ---------------------------------------------------------------------------
__global__ __launch_bounds__(256) void k0_prep(const float* __restrict__ w3,
                                               unsigned short* __restrict__ wbf)
{
    int i = blockIdx.x * 256 + threadIdx.x;
    if (i < 9 * D_ * D_) {
        int t = i >> 10;
        int rem = i & 1023;
        int e = rem >> 5, d = rem & 31;
        wbf[i] = f2bf(w3[((t << 5) + d) * D_ + e]);
    }
}

// ---------------------------------------------------------------------------
// K1: stream x once (coalesced): emit xbf (bf16, swizzled rows), row/col sums,
// then 1x1 conv + sigmoid -> xh,xw (bf16). grid = BG, 512 threads (8 waves).
// Wave wv handles h = wv*8+i. Lane: c4 = lane&7 (16B chan chunk), pxg = lane>>3;
// lane's px set {pxg+8j}. Col partials kept in regs, per-wave LDS slices.
// ---------------------------------------------------------------------------
__global__ __launch_bounds__(512) void k1_means(const float* __restrict__ x,
                                                const float* __restrict__ w1,
                                                const float* __restrict__ b1,
                                                unsigned short* __restrict__ xbf,
                                                unsigned short* __restrict__ xhb,
                                                unsigned short* __restrict__ xwb)
{
    __shared__ float mh[H_][D_];          // row sums (over w)
    __shared__ float mwp[8][W_][D_];      // per-wave col partial sums
    __shared__ float wls[D_ * D_];
    int bg = blockIdx.x;
    int b = bg >> 3, gi = bg & 7;
    const float* base = x + (size_t)b * H_ * W_ * C_ + gi * D_;
    int t = threadIdx.x;
    int lane = t & 63;
    int wv = t >> 6;
    int c4 = lane & 7;
    int pxg = lane >> 3;

    for (int i = t; i < D_ * D_; i += 512) wls[i] = w1[i];

    float4 colp[6];
    #pragma unroll
    for (int j = 0; j < 6; ++j) colp[j] = make_float4(0.f, 0.f, 0.f, 0.f);

    for (int i = 0; i < 8; ++i) {
        int h = (wv << 3) + i;
        const float* rowp = base + (size_t)h * W_ * C_;
        char* xrow = (char*)xbf + (((size_t)bg << 6) + h) * XROWB;
        float4 vj[6];
        #pragma unroll
        for (int j = 0; j < 6; ++j)
            vj[j] = *(const float4*)(rowp + (size_t)(pxg + 8 * j) * C_ + (c4 << 2));
        float4 rp = make_float4(0.f, 0.f, 0.f, 0.f);
        #pragma unroll
        for (int j = 0; j < 6; ++j) {
            float4 v = vj[j];
            int px = pxg + 8 * j;
            // write bf16 swizzled (8B at slot granularity: bit3 preserved by XOR)
            unsigned u0 = (unsigned)f2bf(v.x) | ((unsigned)f2bf(v.y) << 16);
            unsigned u1 = (unsigned)f2bf(v.z) | ((unsigned)f2bf(v.w) << 16);
            int addr = (((px << 6) + (c4 << 3))) ^ ((px & 7) << 4);
            *(uint2*)(xrow + addr) = make_uint2(u0, u1);
            colp[j].x += v.x; colp[j].y += v.y; colp[j].z += v.z; colp[j].w += v.w;
            rp.x += v.x; rp.y += v.y; rp.z += v.z; rp.w += v.w;
        }
        // reduce rp over px groups (lane bits 3..5)
        #pragma unroll
        for (int s = 8; s <= 32; s <<= 1) {
            rp.x += __shfl_xor(rp.x, s); rp.y += __shfl_xor(rp.y, s);
            rp.z += __shfl_xor(rp.z, s); rp.w += __shfl_xor(rp.w, s);
        }
        if (lane < 8) *(float4*)&mh[h][c4 << 2] = rp;
    }
    #pragma unroll
    for (int j = 0; j < 6; ++j)
        *(float4*)&mwp[wv][pxg + 8 * j][c4 << 2] = colp[j];
    __syncthreads();

    // reduce col partials over the 8 waves into mwp[0]
    for (int i = t; i < W_ * D_; i += 512) {
        int px = i >> 5, c = i & 31;
        float s = 0.f;
        #pragma unroll
        for (int v = 0; v < 8; ++v) s += mwp[v][px][c];
        mwp[0][px][c] = s;
    }
    __syncthreads();

    // 1x1 conv + sigmoid, bf16 outputs
    for (int i = t; i < (H_ + W_) * D_; i += 512) {
        int pos = i >> 5, e = i & 31;
        const float* m = (pos < H_) ? mh[pos] : mwp[0][pos - H_];
        float scale = (pos < H_) ? (1.0f / W_) : (1.0f / H_);
        float dot = 0.f;
        #pragma unroll
        for (int d = 0; d < D_; ++d) dot += m[d] * wls[d * D_ + e];
        unsigned short s = f2bf(sigmoidf_(b1[e] + dot * scale));
        if (pos < H_) xhb[(((size_t)bg << 6) + pos) * D_ + e] = s;
        else          xwb[((size_t)bg * W_ + (pos - H_)) * D_ + e] = s;
    }
}

// ---------------------------------------------------------------------------
// K3: MFMA 3x3 conv -> x2 (bf16) + fused x1/LN/s1/s2. grid = BG*8 (8 rows
// each), 256 threads (4 waves). LDS: 10 rows x 48 px x 32ch bf16 = 30720 B,
// filled by global_load_lds width-16 from contiguous pre-swizzled xbf rows.
// ---------------------------------------------------------------------------
__global__ __launch_bounds__(256, 4) void k3_conv(const unsigned short* __restrict__ xbf,
                                                  const unsigned short* __restrict__ wbf,
                                                  const float* __restrict__ b3,
                                                  const unsigned short* __restrict__ xhb,
                                                  const unsigned short* __restrict__ xwb,
                                                  const float* __restrict__ gamma,
                                                  const float* __restrict__ beta,
                                                  unsigned short* __restrict__ x2,
                                                  float* __restrict__ s1,
                                                  float* __restrict__ s2)
{
    __shared__ unsigned short sbuf[10 * W_ * D_];   // 30720 B
    int bi = blockIdx.x;
    int bg = bi >> 3;
    int h0 = (bi & 7) << 3;             // 8 output rows per block
    int t = threadIdx.x;
    int lane = t & 63;
    int wv = t >> 6;

    // weight fragments: 9 taps x 2 N-halves
    const int e0 = lane & 15;
    const int ko = (lane >> 4) << 3;
    bf16x8 wf[9][2];
    #pragma unroll
    for (int tp = 0; tp < 9; ++tp)
        #pragma unroll
        for (int n = 0; n < 2; ++n)
            wf[tp][n] = *(const bf16x8*)(const void*)(wbf + (((tp << 5) + (n << 4) + e0) << 5) + ko);
    float be0 = b3[e0], be1 = b3[e0 + 16];

    // --- stage valid rows via global_load_lds (contiguous in xbf)
    int sA = (h0 == 0) ? 1 : 0;         // first valid LDS row
    int sB = (h0 == 56) ? 8 : 9;        // last valid LDS row
    const char* src = (const char*)xbf + (((size_t)bg << 6) + (h0 - 1 + sA)) * XROWB;
    char* ldsb = (char*)sbuf + sA * XROWB;
    int nch = (sB - sA + 1) * 3;        // 1KB chunks (3072 = 3*1024)
    for (int ch = wv; ch < nch; ch += 4) {
        __builtin_amdgcn_global_load_lds(
            (const __attribute__((address_space(1))) unsigned*)(const void*)(src + (ch << 10) + (lane << 4)),
            (__attribute__((address_space(3))) unsigned*)(void*)(ldsb + (ch << 10)),
            16, 0, 0);
    }
    if (h0 == 0 && t < 192)  *(uint4*)((char*)sbuf + (t << 4)) = make_uint4(0, 0, 0, 0);
    if (h0 == 56 && t < 192) *(uint4*)((char*)sbuf + 9 * XROWB + (t << 4)) = make_uint4(0, 0, 0, 0);
    __syncthreads();

    // per-lane swizzled in-row offsets for the 3 m-tiles x 3 dw taps
    int swz9[9]; bool inv9[9];
    #pragma unroll
    for (int m = 0; m < 3; ++m)
        #pragma unroll
        for (int dw = 0; dw < 3; ++dw) {
            int pxi = (m << 4) + (lane & 15) + dw - 1;
            int pxc = pxi < 0 ? 0 : (pxi > 47 ? 47 : pxi);
            swz9[m * 3 + dw] = swz16(pxc, lane >> 4);
            inv9[m * 3 + dw] = (pxi != pxc);
        }
    const bf16x8 z8 = {0, 0, 0, 0, 0, 0, 0, 0};

    // --- MFMA phase: each wave does 2 rows x 3 m-tiles
    float s2p0 = 0.f, s2p1 = 0.f;
    for (int q = 0; q < 2; ++q) {
        int r = (wv << 1) + q;
        int h = h0 + r;
        #pragma unroll
        for (int m = 0; m < 3; ++m) {
            int w0 = m << 4;
            f32x4 acc0 = {be0, be0, be0, be0};
            f32x4 acc1 = {be1, be1, be1, be1};
            #pragma unroll
            for (int dh = 0; dh < 3; ++dh) {
                int srowB = (r + dh) * XROWB;
                #pragma unroll
                for (int dw = 0; dw < 3; ++dw) {
                    bf16x8 a = *(const bf16x8*)(const void*)((const char*)sbuf + srowB + swz9[m * 3 + dw]);
                    if ((m == 0 && dw == 0) || (m == 2 && dw == 2)) {
                        if (inv9[m * 3 + dw]) a = z8;
                    }
                    acc0 = __builtin_amdgcn_mfma_f32_16x16x32_bf16(a, wf[dh * 3 + dw][0], acc0, 0, 0, 0);
                    acc1 = __builtin_amdgcn_mfma_f32_16x16x32_bf16(a, wf[dh * 3 + dw][1], acc1, 0, 0, 0);
                }
            }
            // D: col=lane&15 (=e), row=(lane>>4)*4+reg (=pixel)
            #pragma unroll
            for (int rg = 0; rg < 4; ++rg) {
                int pw = w0 + ((lane >> 4) << 2) + rg;
                size_t off = (((size_t)bg * H_ + h) * W_ + pw) * D_;
                x2[off + e0]      = f2bf(acc0[rg]);
                x2[off + e0 + 16] = f2bf(acc1[rg]);
                s2p0 += acc0[rg];
                s2p1 += acc1[rg];
            }
        }
    }
    s2p0 += __shfl_xor(s2p0, 16); s2p0 += __shfl_xor(s2p0, 32);
    s2p1 += __shfl_xor(s2p1, 16); s2p1 += __shfl_xor(s2p1, 32);
    if (lane < 16) {
        atomicAdd(&s2[bg * D_ + e0], s2p0);
        atomicAdd(&s2[bg * D_ + e0 + 16], s2p1);
    }

    // --- x1 phase: y = gx*xh*xw, LN, accumulate s1. 384 px, <=2 per thread.
    float s1p[32];
    #pragma unroll
    for (int c = 0; c < 32; ++c) s1p[c] = 0.f;
    for (int pl = t; pl < 8 * W_; pl += 256) {
        int r = pl / W_;
        int w = pl - r * W_;
        int srowB = (r + 1) * XROWB;
        const uint4* ph4 = (const uint4*)(xhb + (((size_t)bg << 6) + h0 + r) * D_);
        const uint4* pw4 = (const uint4*)(xwb + ((size_t)bg * W_ + w) * D_);
        float y[32];
        float mu = 0.f;
        #pragma unroll
        for (int j = 0; j < 4; ++j) {            // 8 channels per slot
            uint4 uv = *(const uint4*)((const char*)sbuf + srowB + swz16(w, j));
            uint4 uh = ph4[j];
            uint4 uw = pw4[j];
            float vv[8], ah[8], aw[8];
            vv[0]=bflo(uv.x); vv[1]=bfhi(uv.x); vv[2]=bflo(uv.y); vv[3]=bfhi(uv.y);
            vv[4]=bflo(uv.z); vv[5]=bfhi(uv.z); vv[6]=bflo(uv.w); vv[7]=bfhi(uv.w);
            ah[0]=bflo(uh.x); ah[1]=bfhi(uh.x); ah[2]=bflo(uh.y); ah[3]=bfhi(uh.y);
            ah[4]=bflo(uh.z); ah[5]=bfhi(uh.z); ah[6]=bflo(uh.w); ah[7]=bfhi(uh.w);
            aw[0]=bflo(uw.x); aw[1]=bfhi(uw.x); aw[2]=bflo(uw.y); aw[3]=bfhi(uw.y);
            aw[4]=bflo(uw.z); aw[5]=bfhi(uw.z); aw[6]=bflo(uw.w); aw[7]=bfhi(uw.w);
            #pragma unroll
            for (int k = 0; k < 8; ++k) {
                float yy = vv[k] * ah[k] * aw[k];
                y[j * 8 + k] = yy;
                mu += yy;
            }
        }
        mu *= (1.0f / D_);
        float var = 0.f;
        #pragma unroll
        for (int c = 0; c < 32; ++c) { float dl = y[c] - mu; var += dl * dl; }
        var *= (1.0f / D_);
        float rs = rsqrtf(var + LN_EPS_);
        #pragma unroll
        for (int c4 = 0; c4 < 8; ++c4) {
            float4 gq = ((const float4*)gamma)[c4];
            float4 bt = ((const float4*)beta)[c4];
            s1p[4 * c4 + 0] += (y[4 * c4 + 0] - mu) * rs * gq.x + bt.x;
            s1p[4 * c4 + 1] += (y[4 * c4 + 1] - mu) * rs * gq.y + bt.y;
            s1p[4 * c4 + 2] += (y[4 * c4 + 2] - mu) * rs * gq.z + bt.z;
            s1p[4 * c4 + 3] += (y[4 * c4 + 3] - mu) * rs * gq.w + bt.w;
        }
    }
    #pragma unroll
    for (int c = 0; c < 32; ++c) {
        float vv = s1p[c];
        vv += __shfl_xor(vv, 1);  vv += __shfl_xor(vv, 2);  vv += __shfl_xor(vv, 4);
        vv += __shfl_xor(vv, 8);  vv += __shfl_xor(vv, 16); vv += __shfl_xor(vv, 32);
        s1p[c] = vv;
    }
    if (lane == 0) {
        #pragma unroll
        for (int c = 0; c < 32; ++c) atomicAdd(&s1[bg * D_ + c], s1p[c]);
    }
}

// ---------------------------------------------------------------------------
// K4: per-bg channel softmax of s1/3072 and s2/3072.
// ---------------------------------------------------------------------------
__global__ __launch_bounds__(64) void k4_softmax(const float* __restrict__ s1,
                                                 const float* __restrict__ s2,
                                                 float* __restrict__ x11,
                                                 float* __restrict__ x21)
{
    int bg = blockIdx.x;
    int lane = threadIdx.x;
    const float* s = (lane < 32) ? s1 : s2;
    float* o = (lane < 32) ? x11 : x21;
    int c = lane & 31;
    float v = s[bg * D_ + c] * (1.0f / (float)NPIX_);
    float m = v;
    m = fmaxf(m, __shfl_xor(m, 1));  m = fmaxf(m, __shfl_xor(m, 2));
    m = fmaxf(m, __shfl_xor(m, 4));  m = fmaxf(m, __shfl_xor(m, 8));
    m = fmaxf(m, __shfl_xor(m, 16));
    float e = expf(v - m);
    float sm = e;
    sm += __shfl_xor(sm, 1);  sm += __shfl_xor(sm, 2);
    sm += __shfl_xor(sm, 4);  sm += __shfl_xor(sm, 8);
    sm += __shfl_xor(sm, 16);
    o[bg * D_ + c] = e / sm;
}

// ---------------------------------------------------------------------------
// K5: final gate. gx from xbf (bf16), recompute x1, read x2 (bf16),
// out = gx * sigmoid(x11.x2 + x21.x1), fp32.
// ---------------------------------------------------------------------------
__global__ __launch_bounds__(192) void k5_final(const unsigned short* __restrict__ xbf,
                                                const unsigned short* __restrict__ xhb,
                                                const unsigned short* __restrict__ xwb,
                                                const float* __restrict__ gamma,
                                                const float* __restrict__ beta,
                                                const unsigned short* __restrict__ x2,
                                                const float* __restrict__ x11,
                                                const float* __restrict__ x21,
                                                float* __restrict__ out)
{
    int bi = blockIdx.x;
    int bg = bi >> 4;
    int h0 = (bi & 15) << 2;
    int tid = threadIdx.x;
    int r = tid / W_;
    int w = tid % W_;
    int h = h0 + r;
    int b = bg >> 3, gi = bg & 7;

    const char* xrow = (const char*)xbf + (((size_t)bg << 6) + h) * XROWB;
    const uint4* ph4 = (const uint4*)(xhb + (((size_t)bg << 6) + h) * D_);
    const uint4* pw4 = (const uint4*)(xwb + ((size_t)bg * W_ + w) * D_);

    float v[32], y[32];
    float mu = 0.f;
    #pragma unroll
    for (int j = 0; j < 4; ++j) {
        uint4 uv = *(const uint4*)(xrow + swz16(w, j));
        uint4 uh = ph4[j];
        uint4 uw = pw4[j];
        float ah[8], aw[8];
        v[j*8+0]=bflo(uv.x); v[j*8+1]=bfhi(uv.x); v[j*8+2]=bflo(uv.y); v[j*8+3]=bfhi(uv.y);
        v[j*8+4]=bflo(uv.z); v[j*8+5]=bfhi(uv.z); v[j*8+6]=bflo(uv.w); v[j*8+7]=bfhi(uv.w);
        ah[0]=bflo(uh.x); ah[1]=bfhi(uh.x); ah[2]=bflo(uh.y); ah[3]=bfhi(uh.y);
        ah[4]=bflo(uh.z); ah[5]=bfhi(uh.z); ah[6]=bflo(uh.w); ah[7]=bfhi(uh.w);
        aw[0]=bflo(uw.x); aw[1]=bfhi(uw.x); aw[2]=bflo(uw.y); aw[3]=bfhi(uw.y);
        aw[4]=bflo(uw.z); aw[5]=bfhi(uw.z); aw[6]=bflo(uw.w); aw[7]=bfhi(uw.w);
        #pragma unroll
        for (int k = 0; k < 8; ++k) {
            float yy = v[j * 8 + k] * ah[k] * aw[k];
            y[j * 8 + k] = yy;
            mu += yy;
        }
    }
    mu *= (1.0f / D_);
    float var = 0.f;
    #pragma unroll
    for (int c = 0; c < D_; ++c) { float dl = y[c] - mu; var += dl * dl; }
    var *= (1.0f / D_);
    float rs = rsqrtf(var + LN_EPS_);

    const uint4* x2q = (const uint4*)(x2 + (((size_t)bg * H_ + h) * W_ + w) * D_);
    float w1 = 0.f, w2 = 0.f;
    #pragma unroll
    for (int j = 0; j < 4; ++j) {
        uint4 u = x2q[j];
        float xv[8];
        xv[0] = bflo(u.x); xv[1] = bfhi(u.x); xv[2] = bflo(u.y); xv[3] = bfhi(u.y);
        xv[4] = bflo(u.z); xv[5] = bfhi(u.z); xv[6] = bflo(u.w); xv[7] = bfhi(u.w);
        #pragma unroll
        for (int k = 0; k < 8; ++k) {
            int c = j * 8 + k;
            float x1v = (y[c] - mu) * rs * gamma[c] + beta[c];
            w1 += x11[bg * D_ + c] * xv[k];
            w2 += x21[bg * D_ + c] * x1v;
        }
    }
    float gate = sigmoidf_(w1 + w2);

    size_t pixoff = (size_t)b * H_ * W_ * C_ + ((size_t)h * W_ + w) * C_ + gi * D_;
    float4* op = (float4*)(out + pixoff);
    #pragma unroll
    for (int q = 0; q < 8; ++q) {
        float4 tq;
        tq.x = v[4 * q + 0] * gate; tq.y = v[4 * q + 1] * gate;
        tq.z = v[4 * q + 2] * gate; tq.w = v[4 * q + 3] * gate;
        op[q] = tq;
    }
}

extern "C" void kernel_launch(void* const* d_in, const int* in_sizes, int n_in,
                              void* d_out, int out_size, void* d_ws, size_t ws_size,
                              hipStream_t stream)
{
    const float* x     = (const float*)d_in[0];
    const float* w1    = (const float*)d_in[1];
    const float* b1    = (const float*)d_in[2];
    const float* w3    = (const float*)d_in[3];
    const float* b3    = (const float*)d_in[4];
    const float* gamma = (const float*)d_in[5];
    const float* beta  = (const float*)d_in[6];

    char* wsb = (char*)d_ws;
    unsigned short* x2  = (unsigned short*)wsb;                      // 50,331,648 B
    unsigned short* xbf = (unsigned short*)(wsb + 50331648);         // 50,331,648 B
    unsigned short* xhb = (unsigned short*)(wsb + 100663296);        //  1,048,576 B
    unsigned short* xwb = (unsigned short*)(wsb + 101711872);        //    786,432 B
    float* s1  = (float*)(wsb + 102498304);                          //     32,768 B
    float* s2  = (float*)(wsb + 102531072);
    float* x11 = (float*)(wsb + 102563840);
    float* x21 = (float*)(wsb + 102596608);
    unsigned short* wbf = (unsigned short*)(wsb + 102629376);        //     18,432 B

    hipMemsetAsync(s1, 0, 65536, stream);   // s1 + s2

    k0_prep<<<36, 256, 0, stream>>>(w3, wbf);
    k1_means<<<BG_, 512, 0, stream>>>(x, w1, b1, xbf, xhb, xwb);
    k3_conv<<<BG_ * 8, 256, 0, stream>>>(xbf, wbf, b3, xhb, xwb, gamma, beta, x2, s1, s2);
    k4_softmax<<<BG_, 64, 0, stream>>>(s1, s2, x11, x21);
    k5_final<<<BG_ * (H_ / 4), 192, 0, stream>>>(xbf, xhb, xwb, gamma, beta, x2, x11, x21,
                                                 (float*)d_out);
}

// Round 7
// 356.948 us; speedup vs baseline: 1.0155x; 1.0155x over previous
//
#include <hip/hip_runtime.h>
#include <math.h>

#define B_ 32
#define H_ 64
#define W_ 48
#define C_ 256
#define G_ 8
#define D_ 32
#define BG_ (B_*G_)          // 256
#define LN_EPS_ 1e-3f
#define NPIX_ (H_*W_)        // 3072
#define XROWB 3072           // bytes per (bg,h) row of xbf: 48 px * 32 ch * 2B

typedef short bf16x8 __attribute__((ext_vector_type(8)));
typedef float f32x4 __attribute__((ext_vector_type(4)));

__device__ __forceinline__ float sigmoidf_(float v) { return 1.0f / (1.0f + expf(-v)); }

// fp32 -> bf16 round-to-nearest-even
__device__ __forceinline__ unsigned short f2bf(float f) {
    unsigned u = __float_as_uint(f);
    u = u + 0x7fffu + ((u >> 16) & 1u);
    return (unsigned short)(u >> 16);
}
__device__ __forceinline__ float bflo(unsigned u) { return __uint_as_float(u << 16); }
__device__ __forceinline__ float bfhi(unsigned u) { return __uint_as_float(u & 0xffff0000u); }

// in-row swizzled byte offset for (px, 16B-slot): linear (px<<6)+(slot<<4), XOR'd
__device__ __forceinline__ int swz16(int px, int slot) {
    return ((px << 6) + (slot << 4)) ^ ((px & 7) << 4);
}

// ---------------------------------------------------------------------------
// K0: transpose+convert conv3x3 weights to bf16, layout wbf[tap][e][d]
// ---------------------------------------------------------------------------
__global__ __launch_bounds__(256) void k0_prep(const float* __restrict__ w3,
                                               unsigned short* __restrict__ wbf)
{
    int i = blockIdx.x * 256 + threadIdx.x;
    if (i < 9 * D_ * D_) {
        int t = i >> 10;
        int rem = i & 1023;
        int e = rem >> 5, d = rem & 31;
        wbf[i] = f2bf(w3[((t << 5) + d) * D_ + e]);
    }
}

// ---------------------------------------------------------------------------
// K1: stream x once (coalesced): emit xbf (bf16, swizzled rows), row/col sums,
// then 1x1 conv + sigmoid -> xh,xw (bf16). grid = BG, 512 threads (8 waves).
// Block bg lands on XCD bg%8 (round-robin) -> xbf/xhb/xwb stay local for k3/k5.
// Rows processed in pairs to double loads in flight.
// ---------------------------------------------------------------------------
__global__ __launch_bounds__(512) void k1_means(const float* __restrict__ x,
                                                const float* __restrict__ w1,
                                                const float* __restrict__ b1,
                                                unsigned short* __restrict__ xbf,
                                                unsigned short* __restrict__ xhb,
                                                unsigned short* __restrict__ xwb)
{
    __shared__ float mh[H_][D_];          // row sums (over w)
    __shared__ float mwp[8][W_][D_];      // per-wave col partial sums
    __shared__ float wls[D_ * D_];
    int bg = blockIdx.x;
    int b = bg >> 3, gi = bg & 7;
    const float* base = x + (size_t)b * H_ * W_ * C_ + gi * D_;
    int t = threadIdx.x;
    int lane = t & 63;
    int wv = t >> 6;
    int c4 = lane & 7;
    int pxg = lane >> 3;

    for (int i = t; i < D_ * D_; i += 512) wls[i] = w1[i];

    float4 colp[6];
    #pragma unroll
    for (int j = 0; j < 6; ++j) colp[j] = make_float4(0.f, 0.f, 0.f, 0.f);

    for (int i = 0; i < 8; i += 2) {
        int ha = (wv << 3) + i;
        int hb = ha + 1;
        const float* rowa = base + (size_t)ha * W_ * C_;
        const float* rowb = base + (size_t)hb * W_ * C_;
        float4 va[6], vb[6];
        #pragma unroll
        for (int j = 0; j < 6; ++j) {
            va[j] = *(const float4*)(rowa + (size_t)(pxg + 8 * j) * C_ + (c4 << 2));
            vb[j] = *(const float4*)(rowb + (size_t)(pxg + 8 * j) * C_ + (c4 << 2));
        }
        char* xrowa = (char*)xbf + (((size_t)bg << 6) + ha) * XROWB;
        char* xrowb = (char*)xbf + (((size_t)bg << 6) + hb) * XROWB;
        float4 rpa = make_float4(0.f, 0.f, 0.f, 0.f);
        float4 rpb = make_float4(0.f, 0.f, 0.f, 0.f);
        #pragma unroll
        for (int j = 0; j < 6; ++j) {
            int px = pxg + 8 * j;
            int addr = (((px << 6) + (c4 << 3))) ^ ((px & 7) << 4);
            float4 v = va[j];
            unsigned u0 = (unsigned)f2bf(v.x) | ((unsigned)f2bf(v.y) << 16);
            unsigned u1 = (unsigned)f2bf(v.z) | ((unsigned)f2bf(v.w) << 16);
            *(uint2*)(xrowa + addr) = make_uint2(u0, u1);
            colp[j].x += v.x; colp[j].y += v.y; colp[j].z += v.z; colp[j].w += v.w;
            rpa.x += v.x; rpa.y += v.y; rpa.z += v.z; rpa.w += v.w;
            float4 u = vb[j];
            unsigned w0 = (unsigned)f2bf(u.x) | ((unsigned)f2bf(u.y) << 16);
            unsigned w1_ = (unsigned)f2bf(u.z) | ((unsigned)f2bf(u.w) << 16);
            *(uint2*)(xrowb + addr) = make_uint2(w0, w1_);
            colp[j].x += u.x; colp[j].y += u.y; colp[j].z += u.z; colp[j].w += u.w;
            rpb.x += u.x; rpb.y += u.y; rpb.z += u.z; rpb.w += u.w;
        }
        #pragma unroll
        for (int s = 8; s <= 32; s <<= 1) {
            rpa.x += __shfl_xor(rpa.x, s); rpa.y += __shfl_xor(rpa.y, s);
            rpa.z += __shfl_xor(rpa.z, s); rpa.w += __shfl_xor(rpa.w, s);
            rpb.x += __shfl_xor(rpb.x, s); rpb.y += __shfl_xor(rpb.y, s);
            rpb.z += __shfl_xor(rpb.z, s); rpb.w += __shfl_xor(rpb.w, s);
        }
        if (lane < 8) {
            *(float4*)&mh[ha][c4 << 2] = rpa;
            *(float4*)&mh[hb][c4 << 2] = rpb;
        }
    }
    #pragma unroll
    for (int j = 0; j < 6; ++j)
        *(float4*)&mwp[wv][pxg + 8 * j][c4 << 2] = colp[j];
    __syncthreads();

    // reduce col partials over the 8 waves into mwp[0]
    for (int i = t; i < W_ * D_; i += 512) {
        int px = i >> 5, c = i & 31;
        float s = 0.f;
        #pragma unroll
        for (int v = 0; v < 8; ++v) s += mwp[v][px][c];
        mwp[0][px][c] = s;
    }
    __syncthreads();

    // 1x1 conv + sigmoid, bf16 outputs
    for (int i = t; i < (H_ + W_) * D_; i += 512) {
        int pos = i >> 5, e = i & 31;
        const float* m = (pos < H_) ? mh[pos] : mwp[0][pos - H_];
        float scale = (pos < H_) ? (1.0f / W_) : (1.0f / H_);
        float dot = 0.f;
        #pragma unroll
        for (int d = 0; d < D_; ++d) dot += m[d] * wls[d * D_ + e];
        unsigned short s = f2bf(sigmoidf_(b1[e] + dot * scale));
        if (pos < H_) xhb[(((size_t)bg << 6) + pos) * D_ + e] = s;
        else          xwb[((size_t)bg * W_ + (pos - H_)) * D_ + e] = s;
    }
}

// ---------------------------------------------------------------------------
// K3: MFMA 3x3 conv -> x2 (bf16) + fused x1/LN/s1/s2. grid = BG*8 (8 rows
// each), 256 threads (4 waves). LDS: 10 rows x 48 px x 32ch bf16 = 30720 B.
// XCD-affine remap: dispatch d -> bg = (d&7) + 8*((d>>3)&31), so every block
// of bg sits on XCD bg%8, matching k1's writer (xbf/xhb/xwb L2-local) and
// making hseg-adjacent halo rows L2-local too.
// ---------------------------------------------------------------------------
__global__ __launch_bounds__(256, 4) void k3_conv(const unsigned short* __restrict__ xbf,
                                                  const unsigned short* __restrict__ wbf,
                                                  const float* __restrict__ b3,
                                                  const unsigned short* __restrict__ xhb,
                                                  const unsigned short* __restrict__ xwb,
                                                  const float* __restrict__ gamma,
                                                  const float* __restrict__ beta,
                                                  unsigned short* __restrict__ x2,
                                                  float* __restrict__ s1,
                                                  float* __restrict__ s2)
{
    __shared__ unsigned short sbuf[10 * W_ * D_];   // 30720 B
    int d = blockIdx.x;
    int k = d >> 3;
    int bg = (d & 7) + ((k & 31) << 3);
    int h0 = (k >> 5) << 3;             // 8 output rows per block
    int t = threadIdx.x;
    int lane = t & 63;
    int wv = t >> 6;

    // weight fragments: 9 taps x 2 N-halves
    const int e0 = lane & 15;
    const int ko = (lane >> 4) << 3;
    bf16x8 wf[9][2];
    #pragma unroll
    for (int tp = 0; tp < 9; ++tp)
        #pragma unroll
        for (int n = 0; n < 2; ++n)
            wf[tp][n] = *(const bf16x8*)(const void*)(wbf + (((tp << 5) + (n << 4) + e0) << 5) + ko);
    float be0 = b3[e0], be1 = b3[e0 + 16];

    // --- stage valid rows via global_load_lds (contiguous in xbf)
    int sA = (h0 == 0) ? 1 : 0;         // first valid LDS row
    int sB = (h0 == 56) ? 8 : 9;        // last valid LDS row
    const char* src = (const char*)xbf + (((size_t)bg << 6) + (h0 - 1 + sA)) * XROWB;
    char* ldsb = (char*)sbuf + sA * XROWB;
    int nch = (sB - sA + 1) * 3;        // 1KB chunks (3072 = 3*1024)
    for (int ch = wv; ch < nch; ch += 4) {
        __builtin_amdgcn_global_load_lds(
            (const __attribute__((address_space(1))) unsigned*)(const void*)(src + (ch << 10) + (lane << 4)),
            (__attribute__((address_space(3))) unsigned*)(void*)(ldsb + (ch << 10)),
            16, 0, 0);
    }
    if (h0 == 0 && t < 192)  *(uint4*)((char*)sbuf + (t << 4)) = make_uint4(0, 0, 0, 0);
    if (h0 == 56 && t < 192) *(uint4*)((char*)sbuf + 9 * XROWB + (t << 4)) = make_uint4(0, 0, 0, 0);
    __syncthreads();

    // per-lane swizzled in-row offsets for the 3 m-tiles x 3 dw taps
    int swz9[9]; bool inv9[9];
    #pragma unroll
    for (int m = 0; m < 3; ++m)
        #pragma unroll
        for (int dw = 0; dw < 3; ++dw) {
            int pxi = (m << 4) + (lane & 15) + dw - 1;
            int pxc = pxi < 0 ? 0 : (pxi > 47 ? 47 : pxi);
            swz9[m * 3 + dw] = swz16(pxc, lane >> 4);
            inv9[m * 3 + dw] = (pxi != pxc);
        }
    const bf16x8 z8 = {0, 0, 0, 0, 0, 0, 0, 0};

    // --- MFMA phase: each wave does 2 rows x 3 m-tiles
    float s2p0 = 0.f, s2p1 = 0.f;
    for (int q = 0; q < 2; ++q) {
        int r = (wv << 1) + q;
        int h = h0 + r;
        #pragma unroll
        for (int m = 0; m < 3; ++m) {
            int w0 = m << 4;
            f32x4 acc0 = {be0, be0, be0, be0};
            f32x4 acc1 = {be1, be1, be1, be1};
            #pragma unroll
            for (int dh = 0; dh < 3; ++dh) {
                int srowB = (r + dh) * XROWB;
                #pragma unroll
                for (int dw = 0; dw < 3; ++dw) {
                    bf16x8 a = *(const bf16x8*)(const void*)((const char*)sbuf + srowB + swz9[m * 3 + dw]);
                    if ((m == 0 && dw == 0) || (m == 2 && dw == 2)) {
                        if (inv9[m * 3 + dw]) a = z8;
                    }
                    acc0 = __builtin_amdgcn_mfma_f32_16x16x32_bf16(a, wf[dh * 3 + dw][0], acc0, 0, 0, 0);
                    acc1 = __builtin_amdgcn_mfma_f32_16x16x32_bf16(a, wf[dh * 3 + dw][1], acc1, 0, 0, 0);
                }
            }
            // D: col=lane&15 (=e), row=(lane>>4)*4+reg (=pixel)
            #pragma unroll
            for (int rg = 0; rg < 4; ++rg) {
                int pw = w0 + ((lane >> 4) << 2) + rg;
                size_t off = (((size_t)bg * H_ + h) * W_ + pw) * D_;
                x2[off + e0]      = f2bf(acc0[rg]);
                x2[off + e0 + 16] = f2bf(acc1[rg]);
                s2p0 += acc0[rg];
                s2p1 += acc1[rg];
            }
        }
    }
    s2p0 += __shfl_xor(s2p0, 16); s2p0 += __shfl_xor(s2p0, 32);
    s2p1 += __shfl_xor(s2p1, 16); s2p1 += __shfl_xor(s2p1, 32);
    if (lane < 16) {
        atomicAdd(&s2[bg * D_ + e0], s2p0);
        atomicAdd(&s2[bg * D_ + e0 + 16], s2p1);
    }

    // --- x1 phase: y = gx*xh*xw, LN, accumulate s1. 384 px, <=2 per thread.
    float s1p[32];
    #pragma unroll
    for (int c = 0; c < 32; ++c) s1p[c] = 0.f;
    for (int pl = t; pl < 8 * W_; pl += 256) {
        int r = pl / W_;
        int w = pl - r * W_;
        int srowB = (r + 1) * XROWB;
        const uint4* ph4 = (const uint4*)(xhb + (((size_t)bg << 6) + h0 + r) * D_);
        const uint4* pw4 = (const uint4*)(xwb + ((size_t)bg * W_ + w) * D_);
        float y[32];
        float mu = 0.f;
        #pragma unroll
        for (int j = 0; j < 4; ++j) {            // 8 channels per slot
            uint4 uv = *(const uint4*)((const char*)sbuf + srowB + swz16(w, j));
            uint4 uh = ph4[j];
            uint4 uw = pw4[j];
            float vv[8], ah[8], aw[8];
            vv[0]=bflo(uv.x); vv[1]=bfhi(uv.x); vv[2]=bflo(uv.y); vv[3]=bfhi(uv.y);
            vv[4]=bflo(uv.z); vv[5]=bfhi(uv.z); vv[6]=bflo(uv.w); vv[7]=bfhi(uv.w);
            ah[0]=bflo(uh.x); ah[1]=bfhi(uh.x); ah[2]=bflo(uh.y); ah[3]=bfhi(uh.y);
            ah[4]=bflo(uh.z); ah[5]=bfhi(uh.z); ah[6]=bflo(uh.w); ah[7]=bfhi(uh.w);
            aw[0]=bflo(uw.x); aw[1]=bfhi(uw.x); aw[2]=bflo(uw.y); aw[3]=bfhi(uw.y);
            aw[4]=bflo(uw.z); aw[5]=bfhi(uw.z); aw[6]=bflo(uw.w); aw[7]=bfhi(uw.w);
            #pragma unroll
            for (int kk = 0; kk < 8; ++kk) {
                float yy = vv[kk] * ah[kk] * aw[kk];
                y[j * 8 + kk] = yy;
                mu += yy;
            }
        }
        mu *= (1.0f / D_);
        float var = 0.f;
        #pragma unroll
        for (int c = 0; c < 32; ++c) { float dl = y[c] - mu; var += dl * dl; }
        var *= (1.0f / D_);
        float rs = rsqrtf(var + LN_EPS_);
        #pragma unroll
        for (int c4 = 0; c4 < 8; ++c4) {
            float4 gq = ((const float4*)gamma)[c4];
            float4 bt = ((const float4*)beta)[c4];
            s1p[4 * c4 + 0] += (y[4 * c4 + 0] - mu) * rs * gq.x + bt.x;
            s1p[4 * c4 + 1] += (y[4 * c4 + 1] - mu) * rs * gq.y + bt.y;
            s1p[4 * c4 + 2] += (y[4 * c4 + 2] - mu) * rs * gq.z + bt.z;
            s1p[4 * c4 + 3] += (y[4 * c4 + 3] - mu) * rs * gq.w + bt.w;
        }
    }
    #pragma unroll
    for (int c = 0; c < 32; ++c) {
        float vv = s1p[c];
        vv += __shfl_xor(vv, 1);  vv += __shfl_xor(vv, 2);  vv += __shfl_xor(vv, 4);
        vv += __shfl_xor(vv, 8);  vv += __shfl_xor(vv, 16); vv += __shfl_xor(vv, 32);
        s1p[c] = vv;
    }
    if (lane == 0) {
        #pragma unroll
        for (int c = 0; c < 32; ++c) atomicAdd(&s1[bg * D_ + c], s1p[c]);
    }
}

// ---------------------------------------------------------------------------
// K4: per-bg channel softmax of s1/3072 and s2/3072. Block bg on XCD bg%8:
// s1/s2 for bg were accumulated by k3 blocks on the same XCD.
// ---------------------------------------------------------------------------
__global__ __launch_bounds__(64) void k4_softmax(const float* __restrict__ s1,
                                                 const float* __restrict__ s2,
                                                 float* __restrict__ x11,
                                                 float* __restrict__ x21)
{
    int bg = blockIdx.x;
    int lane = threadIdx.x;
    const float* s = (lane < 32) ? s1 : s2;
    float* o = (lane < 32) ? x11 : x21;
    int c = lane & 31;
    float v = s[bg * D_ + c] * (1.0f / (float)NPIX_);
    float m = v;
    m = fmaxf(m, __shfl_xor(m, 1));  m = fmaxf(m, __shfl_xor(m, 2));
    m = fmaxf(m, __shfl_xor(m, 4));  m = fmaxf(m, __shfl_xor(m, 8));
    m = fmaxf(m, __shfl_xor(m, 16));
    float e = expf(v - m);
    float sm = e;
    sm += __shfl_xor(sm, 1);  sm += __shfl_xor(sm, 2);
    sm += __shfl_xor(sm, 4);  sm += __shfl_xor(sm, 8);
    sm += __shfl_xor(sm, 16);
    o[bg * D_ + c] = e / sm;
}

// ---------------------------------------------------------------------------
// K5: final gate. gx from xbf (bf16), recompute x1, read x2 (bf16),
// out = gx * sigmoid(x11.x2 + x21.x1), fp32. XCD-affine remap (bg%8).
// ---------------------------------------------------------------------------
__global__ __launch_bounds__(192) void k5_final(const unsigned short* __restrict__ xbf,
                                                const unsigned short* __restrict__ xhb,
                                                const unsigned short* __restrict__ xwb,
                                                const float* __restrict__ gamma,
                                                const float* __restrict__ beta,
                                                const unsigned short* __restrict__ x2,
                                                const float* __restrict__ x11,
                                                const float* __restrict__ x21,
                                                float* __restrict__ out)
{
    int d = blockIdx.x;
    int k = d >> 3;                     // 0..511
    int bg = (d & 7) + ((k & 31) << 3);
    int h0 = (k >> 5) << 2;             // 16 segments x 4 rows
    int tid = threadIdx.x;
    int r = tid / W_;
    int w = tid % W_;
    int h = h0 + r;
    int b = bg >> 3, gi = bg & 7;

    const char* xrow = (const char*)xbf + (((size_t)bg << 6) + h) * XROWB;
    const uint4* ph4 = (const uint4*)(xhb + (((size_t)bg << 6) + h) * D_);
    const uint4* pw4 = (const uint4*)(xwb + ((size_t)bg * W_ + w) * D_);

    float v[32], y[32];
    float mu = 0.f;
    #pragma unroll
    for (int j = 0; j < 4; ++j) {
        uint4 uv = *(const uint4*)(xrow + swz16(w, j));
        uint4 uh = ph4[j];
        uint4 uw = pw4[j];
        float ah[8], aw[8];
        v[j*8+0]=bflo(uv.x); v[j*8+1]=bfhi(uv.x); v[j*8+2]=bflo(uv.y); v[j*8+3]=bfhi(uv.y);
        v[j*8+4]=bflo(uv.z); v[j*8+5]=bfhi(uv.z); v[j*8+6]=bflo(uv.w); v[j*8+7]=bfhi(uv.w);
        ah[0]=bflo(uh.x); ah[1]=bfhi(uh.x); ah[2]=bflo(uh.y); ah[3]=bfhi(uh.y);
        ah[4]=bflo(uh.z); ah[5]=bfhi(uh.z); ah[6]=bflo(uh.w); ah[7]=bfhi(uh.w);
        aw[0]=bflo(uw.x); aw[1]=bfhi(uw.x); aw[2]=bflo(uw.y); aw[3]=bfhi(uw.y);
        aw[4]=bflo(uw.z); aw[5]=bfhi(uw.z); aw[6]=bflo(uw.w); aw[7]=bfhi(uw.w);
        #pragma unroll
        for (int kk = 0; kk < 8; ++kk) {
            float yy = v[j * 8 + kk] * ah[kk] * aw[kk];
            y[j * 8 + kk] = yy;
            mu += yy;
        }
    }
    mu *= (1.0f / D_);
    float var = 0.f;
    #pragma unroll
    for (int c = 0; c < D_; ++c) { float dl = y[c] - mu; var += dl * dl; }
    var *= (1.0f / D_);
    float rs = rsqrtf(var + LN_EPS_);

    const uint4* x2q = (const uint4*)(x2 + (((size_t)bg * H_ + h) * W_ + w) * D_);
    float w1 = 0.f, w2 = 0.f;
    #pragma unroll
    for (int j = 0; j < 4; ++j) {
        uint4 u = x2q[j];
        float xv[8];
        xv[0] = bflo(u.x); xv[1] = bfhi(u.x); xv[2] = bflo(u.y); xv[3] = bfhi(u.y);
        xv[4] = bflo(u.z); xv[5] = bfhi(u.z); xv[6] = bflo(u.w); xv[7] = bfhi(u.w);
        #pragma unroll
        for (int kk = 0; kk < 8; ++kk) {
            int c = j * 8 + kk;
            float x1v = (y[c] - mu) * rs * gamma[c] + beta[c];
            w1 += x11[bg * D_ + c] * xv[kk];
            w2 += x21[bg * D_ + c] * x1v;
        }
    }
    float gate = sigmoidf_(w1 + w2);

    size_t pixoff = (size_t)b * H_ * W_ * C_ + ((size_t)h * W_ + w) * C_ + gi * D_;
    float4* op = (float4*)(out + pixoff);
    #pragma unroll
    for (int q = 0; q < 8; ++q) {
        float4 tq;
        tq.x = v[4 * q + 0] * gate; tq.y = v[4 * q + 1] * gate;
        tq.z = v[4 * q + 2] * gate; tq.w = v[4 * q + 3] * gate;
        op[q] = tq;
    }
}

extern "C" void kernel_launch(void* const* d_in, const int* in_sizes, int n_in,
                              void* d_out, int out_size, void* d_ws, size_t ws_size,
                              hipStream_t stream)
{
    const float* x     = (const float*)d_in[0];
    const float* w1    = (const float*)d_in[1];
    const float* b1    = (const float*)d_in[2];
    const float* w3    = (const float*)d_in[3];
    const float* b3    = (const float*)d_in[4];
    const float* gamma = (const float*)d_in[5];
    const float* beta  = (const float*)d_in[6];

    char* wsb = (char*)d_ws;
    unsigned short* x2  = (unsigned short*)wsb;                      // 50,331,648 B
    unsigned short* xbf = (unsigned short*)(wsb + 50331648);         // 50,331,648 B
    unsigned short* xhb = (unsigned short*)(wsb + 100663296);        //  1,048,576 B
    unsigned short* xwb = (unsigned short*)(wsb + 101711872);        //    786,432 B
    float* s1  = (float*)(wsb + 102498304);                          //     32,768 B
    float* s2  = (float*)(wsb + 102531072);
    float* x11 = (float*)(wsb + 102563840);
    float* x21 = (float*)(wsb + 102596608);
    unsigned short* wbf = (unsigned short*)(wsb + 102629376);        //     18,432 B

    hipMemsetAsync(s1, 0, 65536, stream);   // s1 + s2

    k0_prep<<<36, 256, 0, stream>>>(w3, wbf);
    k1_means<<<BG_, 512, 0, stream>>>(x, w1, b1, xbf, xhb, xwb);
    k3_conv<<<BG_ * 8, 256, 0, stream>>>(xbf, wbf, b3, xhb, xwb, gamma, beta, x2, s1, s2);
    k4_softmax<<<BG_, 64, 0, stream>>>(s1, s2, x11, x21);
    k5_final<<<BG_ * (H_ / 4), 192, 0, stream>>>(xbf, xhb, xwb, gamma, beta, x2, x11, x21,
                                                 (float*)d_out);
}

// Round 10
// 292.616 us; speedup vs baseline: 1.2388x; 1.2199x over previous
//
#include <hip/hip_runtime.h>
#include <math.h>

#define B_ 32
#define H_ 64
#define W_ 48
#define C_ 256
#define G_ 8
#define D_ 32
#define BG_ (B_*G_)          // 256
#define LN_EPS_ 1e-3f
#define NPIX_ (H_*W_)        // 3072
#define SROWB 3072           // bytes per LDS image row: 48 px * 32 ch * 2B

typedef short bf16x8 __attribute__((ext_vector_type(8)));
typedef float f32x4 __attribute__((ext_vector_type(4)));

__device__ __forceinline__ float sigmoidf_(float v) { return 1.0f / (1.0f + expf(-v)); }

__device__ __forceinline__ unsigned short f2bf(float f) {
    unsigned u = __float_as_uint(f);
    u = u + 0x7fffu + ((u >> 16) & 1u);
    return (unsigned short)(u >> 16);
}
__device__ __forceinline__ float bflo(unsigned u) { return __uint_as_float(u << 16); }
__device__ __forceinline__ float bfhi(unsigned u) { return __uint_as_float(u & 0xffff0000u); }

// swizzled in-row byte offset for (px, 16B-slot)
__device__ __forceinline__ int swz16(int px, int slot) {
    return ((px << 6) + (slot << 4)) ^ ((px & 7) << 4);
}

// ---------------------------------------------------------------------------
// K0: conv3x3 weights -> bf16, layout wbf[tap][e][d]
// ---------------------------------------------------------------------------
__global__ __launch_bounds__(256) void k0_prep(const float* __restrict__ w3,
                                               unsigned short* __restrict__ wbf)
{
    int i = blockIdx.x * 256 + threadIdx.x;
    if (i < 9 * D_ * D_) {
        int t = i >> 10;
        int rem = i & 1023;
        int e = rem >> 5, d = rem & 31;
        wbf[i] = f2bf(w3[((t << 5) + d) * D_ + e]);
    }
}

// ---------------------------------------------------------------------------
// K1 mega: per bg (grid=256, 512 thr):
//  pass1: row sums (mh) + col sums (mwp[0]) + corners, reading x once (HBM).
//  1x1 conv + sigmoid -> xhf/xwf (LDS fp32) + xhb/xwb (global bf16).
//  closed-form s2: sum_px conv(gx) = sum_tap w3^T . S_tap + 3072*b3,
//    S_tap = T - excluded_row - excluded_col + corner  (exact algebra, fp32).
//  pass2: re-read x (L3-warm), y=gx*xh*xw, LN -> x1, per-bg s1 (no atomics).
// ---------------------------------------------------------------------------
__global__ __launch_bounds__(512) void k1_means(const float* __restrict__ x,
                                                const float* __restrict__ w1,
                                                const float* __restrict__ b1,
                                                const float* __restrict__ w3,
                                                const float* __restrict__ b3,
                                                const float* __restrict__ gamma,
                                                const float* __restrict__ beta,
                                                unsigned short* __restrict__ xhb,
                                                unsigned short* __restrict__ xwb,
                                                float* __restrict__ s1,
                                                float* __restrict__ s2)
{
    __shared__ float mh[H_][D_];          // raw row sums (over w)
    __shared__ float mwp[8][W_][D_];      // per-wave col partials; mwp[0]=total
    __shared__ float wls[D_ * D_];
    __shared__ float xhf[H_][D_];         // fp32 sigmoid outputs
    __shared__ float xwf[W_][36];         // padded stride 36 (bank spread)
    __shared__ float cst[4][D_];          // corners: 0=(0,0) 1=(0,W-1) 2=(H-1,0) 3=(H-1,W-1)
    __shared__ float Tg[D_];
    __shared__ float Sl[9][D_];
    __shared__ float S2p[9][D_];
    __shared__ float s1red[8][D_];

    int bg = blockIdx.x;
    int b = bg >> 3, gi = bg & 7;
    const float* base = x + (size_t)b * H_ * W_ * C_ + gi * D_;
    int t = threadIdx.x;
    int lane = t & 63;
    int wv = t >> 6;
    int c4 = lane & 7;
    int pxg = lane >> 3;

    for (int i = t; i < D_ * D_; i += 512) wls[i] = w1[i];

    float4 colp[6];
    #pragma unroll
    for (int j = 0; j < 6; ++j) colp[j] = make_float4(0.f, 0.f, 0.f, 0.f);

    for (int i = 0; i < 8; i += 2) {
        int ha = (wv << 3) + i;
        int hb = ha + 1;
        const float* rowa = base + (size_t)ha * W_ * C_;
        const float* rowb = base + (size_t)hb * W_ * C_;
        float4 va[6], vb[6];
        #pragma unroll
        for (int j = 0; j < 6; ++j) {
            va[j] = *(const float4*)(rowa + (size_t)(pxg + 8 * j) * C_ + (c4 << 2));
            vb[j] = *(const float4*)(rowb + (size_t)(pxg + 8 * j) * C_ + (c4 << 2));
        }
        float4 rpa = make_float4(0.f, 0.f, 0.f, 0.f);
        float4 rpb = make_float4(0.f, 0.f, 0.f, 0.f);
        #pragma unroll
        for (int j = 0; j < 6; ++j) {
            float4 v = va[j];
            colp[j].x += v.x; colp[j].y += v.y; colp[j].z += v.z; colp[j].w += v.w;
            rpa.x += v.x; rpa.y += v.y; rpa.z += v.z; rpa.w += v.w;
            float4 u = vb[j];
            colp[j].x += u.x; colp[j].y += u.y; colp[j].z += u.z; colp[j].w += u.w;
            rpb.x += u.x; rpb.y += u.y; rpb.z += u.z; rpb.w += u.w;
        }
        #pragma unroll
        for (int s = 8; s <= 32; s <<= 1) {
            rpa.x += __shfl_xor(rpa.x, s); rpa.y += __shfl_xor(rpa.y, s);
            rpa.z += __shfl_xor(rpa.z, s); rpa.w += __shfl_xor(rpa.w, s);
            rpb.x += __shfl_xor(rpb.x, s); rpb.y += __shfl_xor(rpb.y, s);
            rpb.z += __shfl_xor(rpb.z, s); rpb.w += __shfl_xor(rpb.w, s);
        }
        if (lane < 8) {
            *(float4*)&mh[ha][c4 << 2] = rpa;
            *(float4*)&mh[hb][c4 << 2] = rpb;
        }
    }
    #pragma unroll
    for (int j = 0; j < 6; ++j)
        *(float4*)&mwp[wv][pxg + 8 * j][c4 << 2] = colp[j];
    __syncthreads();

    // reduce col partials into mwp[0]; fetch corners
    for (int i = t; i < W_ * D_; i += 512) {
        int px = i >> 5, c = i & 31;
        float s = 0.f;
        #pragma unroll
        for (int v = 0; v < 8; ++v) s += mwp[v][px][c];
        mwp[0][px][c] = s;
    }
    if (t < 128) {
        int k = t >> 5, c = t & 31;
        int hh = (k >> 1) ? (H_ - 1) : 0;
        int ww = (k & 1) ? (W_ - 1) : 0;
        cst[k][c] = base[(size_t)(hh * W_ + ww) * C_ + c];
    }
    __syncthreads();

    // T + 1x1 conv + sigmoid
    if (t < 32) {
        float s = 0.f;
        for (int h = 0; h < H_; ++h) s += mh[h][t];
        Tg[t] = s;
    }
    for (int i = t; i < (H_ + W_) * D_; i += 512) {
        int pos = i >> 5, e = i & 31;
        const float* m = (pos < H_) ? mh[pos] : mwp[0][pos - H_];
        float scale = (pos < H_) ? (1.0f / W_) : (1.0f / H_);
        float dot = 0.f;
        #pragma unroll
        for (int d = 0; d < D_; ++d) dot += m[d] * wls[d * D_ + e];
        float sg = sigmoidf_(b1[e] + dot * scale);
        if (pos < H_) { xhf[pos][e] = sg; xhb[(((size_t)bg << 6) + pos) * D_ + e] = f2bf(sg); }
        else { xwf[pos - H_][e] = sg; xwb[((size_t)bg * W_ + (pos - H_)) * D_ + e] = f2bf(sg); }
    }
    __syncthreads();

    // S_tap
    if (t < 288) {
        int tap = t >> 5, d = t & 31;
        int dh = tap / 3, dw = tap % 3;
        float S = Tg[d];
        if (dh == 0) S -= mh[H_ - 1][d];
        else if (dh == 2) S -= mh[0][d];
        if (dw == 0) S -= mwp[0][W_ - 1][d];
        else if (dw == 2) S -= mwp[0][0][d];
        if (dh != 1 && dw != 1) S += cst[(dh == 0 ? 2 : 0) + (dw == 0 ? 1 : 0)][d];
        Sl[tap][d] = S;
    }
    __syncthreads();
    if (t < 288) {
        int tap = t >> 5, e = t & 31;
        float a = 0.f;
        #pragma unroll
        for (int d = 0; d < D_; ++d) a += w3[((tap << 5) + d) * D_ + e] * Sl[tap][d];
        S2p[tap][e] = a;
    }
    __syncthreads();
    if (t < 32) {
        float a = (float)NPIX_ * b3[t];
        #pragma unroll
        for (int tap = 0; tap < 9; ++tap) a += S2p[tap][t];
        s2[bg * D_ + t] = a;
    }

    // pass2: s1 (x1 sums), fp32 throughout
    float s1p[32];
    #pragma unroll
    for (int c = 0; c < 32; ++c) s1p[c] = 0.f;
    #pragma unroll
    for (int k = 0; k < 6; ++k) {
        int p = t + (k << 9);
        int h = p / W_;
        int w = p - h * W_;
        const float4* vp = (const float4*)(base + (size_t)(h * W_ + w) * C_);
        float y[32];
        float mu = 0.f;
        #pragma unroll
        for (int j = 0; j < 8; ++j) {
            float4 v = vp[j];
            float4 a = *(const float4*)&xhf[h][j << 2];
            float4 bw = *(const float4*)&xwf[w][j << 2];
            y[4 * j + 0] = v.x * a.x * bw.x;
            y[4 * j + 1] = v.y * a.y * bw.y;
            y[4 * j + 2] = v.z * a.z * bw.z;
            y[4 * j + 3] = v.w * a.w * bw.w;
            mu += y[4 * j + 0] + y[4 * j + 1] + y[4 * j + 2] + y[4 * j + 3];
        }
        mu *= (1.0f / D_);
        float var = 0.f;
        #pragma unroll
        for (int c = 0; c < 32; ++c) { float dl = y[c] - mu; var += dl * dl; }
        var *= (1.0f / D_);
        float rs = rsqrtf(var + LN_EPS_);
        #pragma unroll
        for (int j = 0; j < 8; ++j) {
            float4 gq = ((const float4*)gamma)[j];
            float4 bt = ((const float4*)beta)[j];
            s1p[4 * j + 0] += (y[4 * j + 0] - mu) * rs * gq.x + bt.x;
            s1p[4 * j + 1] += (y[4 * j + 1] - mu) * rs * gq.y + bt.y;
            s1p[4 * j + 2] += (y[4 * j + 2] - mu) * rs * gq.z + bt.z;
            s1p[4 * j + 3] += (y[4 * j + 3] - mu) * rs * gq.w + bt.w;
        }
    }
    #pragma unroll
    for (int c = 0; c < 32; ++c) {
        float vv = s1p[c];
        vv += __shfl_xor(vv, 1);  vv += __shfl_xor(vv, 2);  vv += __shfl_xor(vv, 4);
        vv += __shfl_xor(vv, 8);  vv += __shfl_xor(vv, 16); vv += __shfl_xor(vv, 32);
        s1p[c] = vv;
    }
    if (lane == 0) {
        #pragma unroll
        for (int c = 0; c < 32; ++c) s1red[wv][c] = s1p[c];
    }
    __syncthreads();
    if (t < 32) {
        float a = 0.f;
        #pragma unroll
        for (int v = 0; v < 8; ++v) a += s1red[v][t];
        s1[bg * D_ + t] = a;
    }
}

// ---------------------------------------------------------------------------
// K4: per-bg channel softmax of s1/3072 and s2/3072.
// ---------------------------------------------------------------------------
__global__ __launch_bounds__(64) void k4_softmax(const float* __restrict__ s1,
                                                 const float* __restrict__ s2,
                                                 float* __restrict__ x11,
                                                 float* __restrict__ x21)
{
    int bg = blockIdx.x;
    int lane = threadIdx.x;
    const float* s = (lane < 32) ? s1 : s2;
    float* o = (lane < 32) ? x11 : x21;
    int c = lane & 31;
    float v = s[bg * D_ + c] * (1.0f / (float)NPIX_);
    float m = v;
    m = fmaxf(m, __shfl_xor(m, 1));  m = fmaxf(m, __shfl_xor(m, 2));
    m = fmaxf(m, __shfl_xor(m, 4));  m = fmaxf(m, __shfl_xor(m, 8));
    m = fmaxf(m, __shfl_xor(m, 16));
    float e = expf(v - m);
    float sm = e;
    sm += __shfl_xor(sm, 1);  sm += __shfl_xor(sm, 2);
    sm += __shfl_xor(sm, 4);  sm += __shfl_xor(sm, 8);
    sm += __shfl_xor(sm, 16);
    o[bg * D_ + c] = e / sm;
}

// ---------------------------------------------------------------------------
// K5: fused conv+gate+out. grid = BG*8 (8 rows each), 256 thr (4 waves).
// Stage 10 rows fp32->bf16 swizzled LDS; MFMA conv; w1 = x11.x2 reduced
// in-register from accumulators -> wbuf; then per-pixel x1/w2/gate and
// out = gx_fp32 * gate. No x2 materialization.
// ---------------------------------------------------------------------------
__global__ __launch_bounds__(256) void k5_conv(const float* __restrict__ x,
                                               const unsigned short* __restrict__ wbf,
                                               const float* __restrict__ b3,
                                               const unsigned short* __restrict__ xhb,
                                               const unsigned short* __restrict__ xwb,
                                               const float* __restrict__ gamma,
                                               const float* __restrict__ beta,
                                               const float* __restrict__ x11,
                                               const float* __restrict__ x21,
                                               float* __restrict__ out)
{
    __shared__ unsigned short sbuf[10 * W_ * D_];   // 30720 B
    __shared__ float wbuf[8][W_];                   // w1 per pixel
    int bi = blockIdx.x;
    int bg = bi >> 3;
    int h0 = (bi & 7) << 3;
    int b = bg >> 3, gi = bg & 7;
    const float* base = x + (size_t)b * H_ * W_ * C_ + gi * D_;
    int t = threadIdx.x;
    int lane = t & 63;
    int wv = t >> 6;
    const int e0 = lane & 15;
    const int ko = (lane >> 4) << 3;

    bf16x8 wf[9][2];
    #pragma unroll
    for (int tp = 0; tp < 9; ++tp)
        #pragma unroll
        for (int n = 0; n < 2; ++n)
            wf[tp][n] = *(const bf16x8*)(const void*)(wbf + (((tp << 5) + (n << 4) + e0) << 5) + ko);
    float be0 = b3[e0], be1 = b3[e0 + 16];
    float a110 = x11[bg * D_ + e0], a111 = x11[bg * D_ + e0 + 16];

    // stage 10 rows (h0-1 .. h0+8), zero-fill outside image
    #pragma unroll
    for (int kk = 0; kk < 15; ++kk) {
        int i = t + (kk << 8);
        int r = i / 384;
        int rem = i - r * 384;
        int w = rem >> 3, cc = rem & 7;
        int hh = h0 - 1 + r;
        unsigned u0 = 0, u1 = 0;
        if (hh >= 0 && hh < H_) {
            float4 v = *(const float4*)(base + (size_t)(hh * W_ + w) * C_ + (cc << 2));
            u0 = (unsigned)f2bf(v.x) | ((unsigned)f2bf(v.y) << 16);
            u1 = (unsigned)f2bf(v.z) | ((unsigned)f2bf(v.w) << 16);
        }
        int addr = r * SROWB + ((((w << 6) + (cc << 3))) ^ ((w & 7) << 4));
        *(uint2*)((char*)sbuf + addr) = make_uint2(u0, u1);
    }
    __syncthreads();

    int swz9[9]; bool inv9[9];
    #pragma unroll
    for (int m = 0; m < 3; ++m)
        #pragma unroll
        for (int dw = 0; dw < 3; ++dw) {
            int pxi = (m << 4) + e0 + dw - 1;
            int pxc = pxi < 0 ? 0 : (pxi > 47 ? 47 : pxi);
            swz9[m * 3 + dw] = swz16(pxc, lane >> 4);
            inv9[m * 3 + dw] = (pxi != pxc);
        }
    const bf16x8 z8 = {0, 0, 0, 0, 0, 0, 0, 0};

    for (int q = 0; q < 2; ++q) {
        int r = (wv << 1) + q;
        #pragma unroll
        for (int m = 0; m < 3; ++m) {
            f32x4 acc0 = {be0, be0, be0, be0};
            f32x4 acc1 = {be1, be1, be1, be1};
            #pragma unroll
            for (int dh = 0; dh < 3; ++dh) {
                int srowB = (r + dh) * SROWB;
                #pragma unroll
                for (int dw = 0; dw < 3; ++dw) {
                    bf16x8 a = *(const bf16x8*)(const void*)((const char*)sbuf + srowB + swz9[m * 3 + dw]);
                    if ((m == 0 && dw == 0) || (m == 2 && dw == 2)) {
                        if (inv9[m * 3 + dw]) a = z8;
                    }
                    acc0 = __builtin_amdgcn_mfma_f32_16x16x32_bf16(a, wf[dh * 3 + dw][0], acc0, 0, 0, 0);
                    acc1 = __builtin_amdgcn_mfma_f32_16x16x32_bf16(a, wf[dh * 3 + dw][1], acc1, 0, 0, 0);
                }
            }
            // w1[pixel] = sum_e x11[e]*x2[pixel][e]; acc D-layout: col=e0, row=pixel
            #pragma unroll
            for (int rg = 0; rg < 4; ++rg) {
                float p = a110 * acc0[rg] + a111 * acc1[rg];
                p += __shfl_xor(p, 1); p += __shfl_xor(p, 2);
                p += __shfl_xor(p, 4); p += __shfl_xor(p, 8);
                if (e0 == 0) wbuf[r][(m << 4) + ((lane >> 4) << 2) + rg] = p;
            }
        }
    }
    __syncthreads();

    // per-pixel epilogue
    for (int p = t; p < 8 * W_; p += 256) {
        int r = p / W_;
        int w = p - r * W_;
        int h = h0 + r;
        int srowB = (r + 1) * SROWB;
        const uint4* ph4 = (const uint4*)(xhb + (((size_t)bg << 6) + h) * D_);
        const uint4* pw4 = (const uint4*)(xwb + ((size_t)bg * W_ + w) * D_);
        float y[32];
        float mu = 0.f;
        #pragma unroll
        for (int j = 0; j < 4; ++j) {
            uint4 uv = *(const uint4*)((const char*)sbuf + srowB + swz16(w, j));
            uint4 uh = ph4[j];
            uint4 uw = pw4[j];
            float vv[8], ah[8], aw[8];
            vv[0]=bflo(uv.x); vv[1]=bfhi(uv.x); vv[2]=bflo(uv.y); vv[3]=bfhi(uv.y);
            vv[4]=bflo(uv.z); vv[5]=bfhi(uv.z); vv[6]=bflo(uv.w); vv[7]=bfhi(uv.w);
            ah[0]=bflo(uh.x); ah[1]=bfhi(uh.x); ah[2]=bflo(uh.y); ah[3]=bfhi(uh.y);
            ah[4]=bflo(uh.z); ah[5]=bfhi(uh.z); ah[6]=bflo(uh.w); ah[7]=bfhi(uh.w);
            aw[0]=bflo(uw.x); aw[1]=bfhi(uw.x); aw[2]=bflo(uw.y); aw[3]=bfhi(uw.y);
            aw[4]=bflo(uw.z); aw[5]=bfhi(uw.z); aw[6]=bflo(uw.w); aw[7]=bfhi(uw.w);
            #pragma unroll
            for (int kk = 0; kk < 8; ++kk) {
                float yy = vv[kk] * ah[kk] * aw[kk];
                y[j * 8 + kk] = yy;
                mu += yy;
            }
        }
        mu *= (1.0f / D_);
        float var = 0.f;
        #pragma unroll
        for (int c = 0; c < D_; ++c) { float dl = y[c] - mu; var += dl * dl; }
        var *= (1.0f / D_);
        float rs = rsqrtf(var + LN_EPS_);

        float w2 = 0.f;
        #pragma unroll
        for (int c = 0; c < D_; ++c) {
            float x1v = (y[c] - mu) * rs * gamma[c] + beta[c];
            w2 += x21[bg * D_ + c] * x1v;
        }
        float gate = sigmoidf_(wbuf[r][w] + w2);

        const float4* vp = (const float4*)(base + (size_t)(h * W_ + w) * C_);
        float4* op = (float4*)(out + (size_t)b * H_ * W_ * C_ + (size_t)(h * W_ + w) * C_ + gi * D_);
        #pragma unroll
        for (int j = 0; j < 8; ++j) {
            float4 vv = vp[j];
            float4 tq;
            tq.x = vv.x * gate; tq.y = vv.y * gate;
            tq.z = vv.z * gate; tq.w = vv.w * gate;
            op[j] = tq;
        }
    }
}

extern "C" void kernel_launch(void* const* d_in, const int* in_sizes, int n_in,
                              void* d_out, int out_size, void* d_ws, size_t ws_size,
                              hipStream_t stream)
{
    const float* x     = (const float*)d_in[0];
    const float* w1    = (const float*)d_in[1];
    const float* b1    = (const float*)d_in[2];
    const float* w3    = (const float*)d_in[3];
    const float* b3    = (const float*)d_in[4];
    const float* gamma = (const float*)d_in[5];
    const float* beta  = (const float*)d_in[6];

    char* wsb = (char*)d_ws;
    unsigned short* xhb = (unsigned short*)wsb;                 // 1,048,576 B
    unsigned short* xwb = (unsigned short*)(wsb + 1048576);     //   786,432 B
    float* s1  = (float*)(wsb + 1835008);                       //    32,768 B
    float* s2  = (float*)(wsb + 1867776);
    float* x11 = (float*)(wsb + 1900544);
    float* x21 = (float*)(wsb + 1933312);
    unsigned short* wbf = (unsigned short*)(wsb + 1966080);     //    18,432 B

    k0_prep<<<36, 256, 0, stream>>>(w3, wbf);
    k1_means<<<BG_, 512, 0, stream>>>(x, w1, b1, w3, b3, gamma, beta, xhb, xwb, s1, s2);
    k4_softmax<<<BG_, 64, 0, stream>>>(s1, s2, x11, x21);
    k5_conv<<<BG_ * 8, 256, 0, stream>>>(x, wbf, b3, xhb, xwb, gamma, beta, x11, x21,
                                         (float*)d_out);
}